// Round 4
// baseline (969.530 us; speedup 1.0000x reference)
//
#include <hip/hip_runtime.h>
#include <hip/hip_bf16.h>
#include <math.h>

// ---------------------------------------------------------------------------
// GraphSAGE 2-layer forward, fp32.
// Key algebraic opt: mean_j(x_j) @ W_r == mean_j(x_j @ W_r)  -> project first,
// aggregate 64/40-dim vectors instead of 256-dim. Shared CSR for both layers.
// ---------------------------------------------------------------------------

#define WAVE 64

// ---------------- CSR build ----------------

__global__ void k_count(const int* __restrict__ dst, int* __restrict__ cnt, int E) {
    int e = blockIdx.x * blockDim.x + threadIdx.x;
    if (e < E) atomicAdd(&cnt[dst[e]], 1);
}

__global__ void k_blocksum(const int* __restrict__ cnt, int* __restrict__ bsum, int N) {
    __shared__ int sm[256];
    int i = blockIdx.x * 256 + threadIdx.x;
    sm[threadIdx.x] = (i < N) ? cnt[i] : 0;
    __syncthreads();
    for (int s = 128; s > 0; s >>= 1) {
        if (threadIdx.x < s) sm[threadIdx.x] += sm[threadIdx.x + s];
        __syncthreads();
    }
    if (threadIdx.x == 0) bsum[blockIdx.x] = sm[0];
}

// single block, 512 threads: exclusive scan of bsum[0..nb)
__global__ void k_scanbsum(int* __restrict__ bsum, int nb) {
    __shared__ int a[512], b[512];
    int t = threadIdx.x;
    int v = (t < nb) ? bsum[t] : 0;
    a[t] = v;
    __syncthreads();
    int* pin = a; int* pout = b;
    for (int o = 1; o < 512; o <<= 1) {
        pout[t] = (t >= o) ? pin[t] + pin[t - o] : pin[t];
        __syncthreads();
        int* tmp = pin; pin = pout; pout = tmp;
    }
    if (t < nb) bsum[t] = pin[t] - v;   // exclusive
}

__global__ void k_scanfinal(const int* __restrict__ cnt, const int* __restrict__ bsum,
                            int* __restrict__ off, int* __restrict__ cursor, int N) {
    __shared__ int a[256], b[256];
    int t = threadIdx.x;
    int i = blockIdx.x * 256 + t;
    int v = (i < N) ? cnt[i] : 0;
    a[t] = v;
    __syncthreads();
    int* pin = a; int* pout = b;
    for (int o = 1; o < 256; o <<= 1) {
        pout[t] = (t >= o) ? pin[t] + pin[t - o] : pin[t];
        __syncthreads();
        int* tmp = pin; pin = pout; pout = tmp;
    }
    if (i < N) {
        int ex = bsum[blockIdx.x] + pin[t] - v;   // exclusive within-block + base
        off[i] = ex;
        cursor[i] = ex;
    }
}

__global__ void k_scatter(const int* __restrict__ src, const int* __restrict__ dst,
                          int* __restrict__ cursor, int* __restrict__ csr, int E) {
    int e = blockIdx.x * blockDim.x + threadIdx.x;
    if (e < E) {
        int d = dst[e];
        int pos = atomicAdd(&cursor[d], 1);
        csr[pos] = src[e];
    }
}

// ---------------- GEMM1: y1[N,128] = x[N,256] @ [W1_l | W1_r] ----------------
// block 256 thr, tile 64 rows x 128 cols, k-chunk 32.
// thread (rg=tid>>5, cg=tid&31) computes rows rg*8..+8, cols cg*4..+4.

__global__ __launch_bounds__(256) void k_gemm1(const float* __restrict__ x,
                                               const float* __restrict__ Wl,
                                               const float* __restrict__ Wr,
                                               float* __restrict__ y1, int N) {
    __shared__ float xs[64][36];     // 32 used + pad
    __shared__ float wsm[32][128];
    int tid = threadIdx.x;
    int row0 = blockIdx.x * 64;
    int rg = tid >> 5;
    int cg = tid & 31;
    int r0 = rg * 8;
    int c0 = cg * 4;
    float acc[8][4];
    #pragma unroll
    for (int i = 0; i < 8; ++i)
        #pragma unroll
        for (int j = 0; j < 4; ++j) acc[i][j] = 0.f;

    for (int kk = 0; kk < 256; kk += 32) {
        // stage x tile: 64 x 32 = 512 float4, 2 per thread
        #pragma unroll
        for (int it = 0; it < 2; ++it) {
            int idx = tid + it * 256;
            int r = idx >> 3;
            int kq = idx & 7;
            int row = row0 + r;
            float4 v = make_float4(0.f, 0.f, 0.f, 0.f);
            if (row < N) v = *(const float4*)(x + (size_t)row * 256 + kk + kq * 4);
            *(float4*)(&xs[r][kq * 4]) = v;
        }
        // stage w tile: 32 x 128 = 1024 float4, 4 per thread
        #pragma unroll
        for (int it = 0; it < 4; ++it) {
            int idx = tid + it * 256;
            int k = idx >> 5;
            int cq = idx & 31;
            const float* s = (cq < 16) ? (Wl + (size_t)(kk + k) * 64 + cq * 4)
                                       : (Wr + (size_t)(kk + k) * 64 + (cq - 16) * 4);
            *(float4*)(&wsm[k][cq * 4]) = *(const float4*)s;
        }
        __syncthreads();
        #pragma unroll
        for (int k4 = 0; k4 < 32; k4 += 4) {
            float4 xv[8];
            #pragma unroll
            for (int i = 0; i < 8; ++i) xv[i] = *(const float4*)(&xs[r0 + i][k4]);
            float4 wv0 = *(const float4*)(&wsm[k4 + 0][c0]);
            float4 wv1 = *(const float4*)(&wsm[k4 + 1][c0]);
            float4 wv2 = *(const float4*)(&wsm[k4 + 2][c0]);
            float4 wv3 = *(const float4*)(&wsm[k4 + 3][c0]);
            #pragma unroll
            for (int i = 0; i < 8; ++i) {
                acc[i][0] += xv[i].x * wv0.x + xv[i].y * wv1.x + xv[i].z * wv2.x + xv[i].w * wv3.x;
                acc[i][1] += xv[i].x * wv0.y + xv[i].y * wv1.y + xv[i].z * wv2.y + xv[i].w * wv3.y;
                acc[i][2] += xv[i].x * wv0.z + xv[i].y * wv1.z + xv[i].z * wv2.z + xv[i].w * wv3.z;
                acc[i][3] += xv[i].x * wv0.w + xv[i].y * wv1.w + xv[i].z * wv2.w + xv[i].w * wv3.w;
            }
        }
        __syncthreads();
    }
    #pragma unroll
    for (int i = 0; i < 8; ++i) {
        int row = row0 + r0 + i;
        if (row < N) {
            float4 v = make_float4(acc[i][0], acc[i][1], acc[i][2], acc[i][3]);
            *(float4*)(y1 + (size_t)row * 128 + c0) = v;
        }
    }
}

// ---------------- Agg1 + epilogue: h = relu(xl + mean(xr[src]) + b1) ---------

__global__ void k_agg1(const float* __restrict__ y1, const int* __restrict__ csr,
                       const int* __restrict__ off, const int* __restrict__ cnt,
                       const float* __restrict__ b1, float* __restrict__ h, int N) {
    int lane = threadIdx.x & 63;
    int wid = (blockIdx.x * blockDim.x + threadIdx.x) >> 6;
    int nw = (gridDim.x * blockDim.x) >> 6;
    for (int i = wid; i < N; i += nw) {
        int deg = cnt[i];
        int start = off[i];
        float a0 = 0.f, a1 = 0.f, a2 = 0.f, a3 = 0.f;
        for (int base = 0; base < deg; base += 64) {
            int m = min(64, deg - base);
            int s = (lane < m) ? csr[start + base + lane] : 0;
            int j = 0;
            for (; j + 4 <= m; j += 4) {
                int s0 = __shfl(s, j), s1 = __shfl(s, j + 1);
                int s2 = __shfl(s, j + 2), s3 = __shfl(s, j + 3);
                float v0 = y1[(size_t)s0 * 128 + 64 + lane];
                float v1 = y1[(size_t)s1 * 128 + 64 + lane];
                float v2 = y1[(size_t)s2 * 128 + 64 + lane];
                float v3 = y1[(size_t)s3 * 128 + 64 + lane];
                a0 += v0; a1 += v1; a2 += v2; a3 += v3;
            }
            for (; j < m; ++j) {
                int sj = __shfl(s, j);
                a0 += y1[(size_t)sj * 128 + 64 + lane];
            }
        }
        float mean = (a0 + a1 + a2 + a3) / (float)max(deg, 1);
        float v = y1[(size_t)i * 128 + lane] + mean + b1[lane];
        h[(size_t)i * 64 + lane] = fmaxf(v, 0.f);
    }
}

// ---------------- GEMM2: y2[N,80] = h[N,64] @ [W2_l | W2_r] -----------------
// block 320 thr (5 waves), tile 32 rows x 80 cols, full K=64 staged.

__global__ __launch_bounds__(320) void k_gemm2(const float* __restrict__ h,
                                               const float* __restrict__ Wl,
                                               const float* __restrict__ Wr,
                                               float* __restrict__ y2, int N) {
    __shared__ float hs[32][68];
    __shared__ float wsm[64][80];
    int tid = threadIdx.x;
    int row0 = blockIdx.x * 32;
    // stage W: 64*80 = 1280 float4, exactly 4 per thread
    #pragma unroll
    for (int it = 0; it < 4; ++it) {
        int idx = tid + it * 320;
        int k = idx / 20;
        int cq = idx % 20;
        const float* s = (cq < 10) ? (Wl + (size_t)k * 40 + cq * 4)
                                   : (Wr + (size_t)k * 40 + (cq - 10) * 4);
        *(float4*)(&wsm[k][cq * 4]) = *(const float4*)s;
    }
    // stage h tile: 32*64 = 512 float4
    for (int idx = tid; idx < 512; idx += 320) {
        int r = idx >> 4;
        int kq = idx & 15;
        int row = row0 + r;
        float4 v = make_float4(0.f, 0.f, 0.f, 0.f);
        if (row < N) v = *(const float4*)(h + (size_t)row * 64 + kq * 4);
        *(float4*)(&hs[r][kq * 4]) = v;
    }
    __syncthreads();
    int c = tid % 80;
    int rg = tid / 80;      // 0..3
    int r0 = rg * 8;
    float acc[8];
    #pragma unroll
    for (int i = 0; i < 8; ++i) acc[i] = 0.f;
    #pragma unroll
    for (int k4 = 0; k4 < 64; k4 += 4) {
        float4 hv[8];
        #pragma unroll
        for (int i = 0; i < 8; ++i) hv[i] = *(const float4*)(&hs[r0 + i][k4]);
        float w0 = wsm[k4 + 0][c];
        float w1 = wsm[k4 + 1][c];
        float w2 = wsm[k4 + 2][c];
        float w3 = wsm[k4 + 3][c];
        #pragma unroll
        for (int i = 0; i < 8; ++i)
            acc[i] += hv[i].x * w0 + hv[i].y * w1 + hv[i].z * w2 + hv[i].w * w3;
    }
    #pragma unroll
    for (int i = 0; i < 8; ++i) {
        int row = row0 + r0 + i;
        if (row < N) y2[(size_t)row * 80 + c] = acc[i];
    }
}

// ---------------- Agg2 + bias + softmax -------------------------------------

__global__ void k_agg2(const float* __restrict__ y2, const int* __restrict__ csr,
                       const int* __restrict__ off, const int* __restrict__ cnt,
                       const float* __restrict__ b2, float* __restrict__ out, int N) {
    int lane = threadIdx.x & 63;
    int wid = (blockIdx.x * blockDim.x + threadIdx.x) >> 6;
    int nw = (gridDim.x * blockDim.x) >> 6;
    for (int i = wid; i < N; i += nw) {
        int deg = cnt[i];
        int start = off[i];
        float a0 = 0.f, a1 = 0.f, a2 = 0.f, a3 = 0.f;
        bool act = (lane < 40);
        for (int base = 0; base < deg; base += 64) {
            int m = min(64, deg - base);
            int s = (lane < m) ? csr[start + base + lane] : 0;
            int j = 0;
            for (; j + 4 <= m; j += 4) {
                int s0 = __shfl(s, j), s1 = __shfl(s, j + 1);
                int s2 = __shfl(s, j + 2), s3 = __shfl(s, j + 3);
                if (act) {
                    a0 += y2[(size_t)s0 * 80 + 40 + lane];
                    a1 += y2[(size_t)s1 * 80 + 40 + lane];
                    a2 += y2[(size_t)s2 * 80 + 40 + lane];
                    a3 += y2[(size_t)s3 * 80 + 40 + lane];
                }
            }
            for (; j < m; ++j) {
                int sj = __shfl(s, j);
                if (act) a0 += y2[(size_t)sj * 80 + 40 + lane];
            }
        }
        float logit = -INFINITY;
        if (act) {
            float mean = (a0 + a1 + a2 + a3) / (float)max(deg, 1);
            logit = y2[(size_t)i * 80 + lane] + mean + b2[lane];
        }
        float mx = logit;
        #pragma unroll
        for (int o = 32; o > 0; o >>= 1) mx = fmaxf(mx, __shfl_xor(mx, o));
        float e = act ? expf(logit - mx) : 0.f;
        float se = e;
        #pragma unroll
        for (int o = 32; o > 0; o >>= 1) se += __shfl_xor(se, o);
        if (act) out[(size_t)i * 40 + lane] = e / se;
    }
}

// ---------------- launch ----------------------------------------------------

extern "C" void kernel_launch(void* const* d_in, const int* in_sizes, int n_in,
                              void* d_out, int out_size, void* d_ws, size_t ws_size,
                              hipStream_t stream) {
    const float* x   = (const float*)d_in[0];
    const int*   ei  = (const int*)d_in[1];
    const float* W1l = (const float*)d_in[2];
    const float* W1r = (const float*)d_in[3];
    const float* b1  = (const float*)d_in[4];
    const float* W2l = (const float*)d_in[5];
    const float* W2r = (const float*)d_in[6];
    const float* b2  = (const float*)d_in[7];
    float* out = (float*)d_out;

    int N = in_sizes[0] / 256;
    int E = in_sizes[1] / 2;
    const int* srcp = ei;
    const int* dstp = ei + E;

    char* w = (char*)d_ws;
    auto alloc = [&](size_t bytes) {
        char* p = w;
        w += (bytes + 255) & ~(size_t)255;
        return p;
    };
    int nb = (N + 255) / 256;
    int*   cnt    = (int*)alloc((size_t)N * 4);
    int*   off    = (int*)alloc((size_t)N * 4);
    int*   cursor = (int*)alloc((size_t)N * 4);
    int*   bsum   = (int*)alloc((size_t)nb * 4);
    int*   csr    = (int*)alloc((size_t)E * 4);
    float* y1     = (float*)alloc((size_t)N * 128 * 4);
    float* h      = (float*)alloc((size_t)N * 64 * 4);
    float* y2     = (float*)alloc((size_t)N * 80 * 4);

    hipMemsetAsync(cnt, 0, (size_t)N * 4, stream);
    k_count<<<(E + 255) / 256, 256, 0, stream>>>(dstp, cnt, E);
    k_blocksum<<<nb, 256, 0, stream>>>(cnt, bsum, N);
    k_scanbsum<<<1, 512, 0, stream>>>(bsum, nb);
    k_scanfinal<<<nb, 256, 0, stream>>>(cnt, bsum, off, cursor, N);
    k_scatter<<<(E + 255) / 256, 256, 0, stream>>>(srcp, dstp, cursor, csr, E);

    k_gemm1<<<(N + 63) / 64, 256, 0, stream>>>(x, W1l, W1r, y1, N);
    k_agg1<<<2048, 256, 0, stream>>>(y1, csr, off, cnt, b1, h, N);
    k_gemm2<<<(N + 31) / 32, 320, 0, stream>>>(h, W2l, W2r, y2, N);
    k_agg2<<<2048, 256, 0, stream>>>(y2, csr, off, cnt, b2, out, N);
}

// Round 5
// 545.283 us; speedup vs baseline: 1.7780x; 1.7780x over previous
//
#include <hip/hip_runtime.h>
#include <hip/hip_bf16.h>
#include <math.h>

// ---------------------------------------------------------------------------
// GraphSAGE 2-layer forward, fp32.
// mean_j(x_j) @ W_r == mean_j(x_j @ W_r) -> project first, aggregate small.
// R5 change: fuse layer-2 GEMV (h[i] @ [W2l|W2r]) into the agg1 epilogue;
// eliminates the k_gemm2 dispatch (440us, inexplicable 1.68GB HBM traffic)
// and the h buffer round-trip entirely.
// ---------------------------------------------------------------------------

// ---------------- CSR build ----------------

__global__ void k_count(const int* __restrict__ dst, int* __restrict__ cnt, int E) {
    int e = blockIdx.x * blockDim.x + threadIdx.x;
    if (e < E) atomicAdd(&cnt[dst[e]], 1);
}

__global__ void k_blocksum(const int* __restrict__ cnt, int* __restrict__ bsum, int N) {
    __shared__ int sm[256];
    int i = blockIdx.x * 256 + threadIdx.x;
    sm[threadIdx.x] = (i < N) ? cnt[i] : 0;
    __syncthreads();
    for (int s = 128; s > 0; s >>= 1) {
        if (threadIdx.x < s) sm[threadIdx.x] += sm[threadIdx.x + s];
        __syncthreads();
    }
    if (threadIdx.x == 0) bsum[blockIdx.x] = sm[0];
}

// single block, 512 threads: exclusive scan of bsum[0..nb)
__global__ void k_scanbsum(int* __restrict__ bsum, int nb) {
    __shared__ int a[512], b[512];
    int t = threadIdx.x;
    int v = (t < nb) ? bsum[t] : 0;
    a[t] = v;
    __syncthreads();
    int* pin = a; int* pout = b;
    for (int o = 1; o < 512; o <<= 1) {
        pout[t] = (t >= o) ? pin[t] + pin[t - o] : pin[t];
        __syncthreads();
        int* tmp = pin; pin = pout; pout = tmp;
    }
    if (t < nb) bsum[t] = pin[t] - v;   // exclusive
}

__global__ void k_scanfinal(const int* __restrict__ cnt, const int* __restrict__ bsum,
                            int* __restrict__ off, int* __restrict__ cursor, int N) {
    __shared__ int a[256], b[256];
    int t = threadIdx.x;
    int i = blockIdx.x * 256 + t;
    int v = (i < N) ? cnt[i] : 0;
    a[t] = v;
    __syncthreads();
    int* pin = a; int* pout = b;
    for (int o = 1; o < 256; o <<= 1) {
        pout[t] = (t >= o) ? pin[t] + pin[t - o] : pin[t];
        __syncthreads();
        int* tmp = pin; pin = pout; pout = tmp;
    }
    if (i < N) {
        int ex = bsum[blockIdx.x] + pin[t] - v;   // exclusive within-block + base
        off[i] = ex;
        cursor[i] = ex;
    }
}

__global__ void k_scatter(const int* __restrict__ src, const int* __restrict__ dst,
                          int* __restrict__ cursor, int* __restrict__ csr, int E) {
    int e = blockIdx.x * blockDim.x + threadIdx.x;
    if (e < E) {
        int d = dst[e];
        int pos = atomicAdd(&cursor[d], 1);
        csr[pos] = src[e];
    }
}

// ---------------- GEMM1: y1[N,128] = x[N,256] @ [W1_l | W1_r] ----------------

__global__ __launch_bounds__(256) void k_gemm1(const float* __restrict__ x,
                                               const float* __restrict__ Wl,
                                               const float* __restrict__ Wr,
                                               float* __restrict__ y1, int N) {
    __shared__ float xs[64][36];
    __shared__ float wsm[32][128];
    int tid = threadIdx.x;
    int row0 = blockIdx.x * 64;
    int rg = tid >> 5;
    int cg = tid & 31;
    int r0 = rg * 8;
    int c0 = cg * 4;
    float acc[8][4];
    #pragma unroll
    for (int i = 0; i < 8; ++i)
        #pragma unroll
        for (int j = 0; j < 4; ++j) acc[i][j] = 0.f;

    for (int kk = 0; kk < 256; kk += 32) {
        #pragma unroll
        for (int it = 0; it < 2; ++it) {
            int idx = tid + it * 256;
            int r = idx >> 3;
            int kq = idx & 7;
            int row = row0 + r;
            float4 v = make_float4(0.f, 0.f, 0.f, 0.f);
            if (row < N) v = *(const float4*)(x + (size_t)row * 256 + kk + kq * 4);
            *(float4*)(&xs[r][kq * 4]) = v;
        }
        #pragma unroll
        for (int it = 0; it < 4; ++it) {
            int idx = tid + it * 256;
            int k = idx >> 5;
            int cq = idx & 31;
            const float* s = (cq < 16) ? (Wl + (size_t)(kk + k) * 64 + cq * 4)
                                       : (Wr + (size_t)(kk + k) * 64 + (cq - 16) * 4);
            *(float4*)(&wsm[k][cq * 4]) = *(const float4*)s;
        }
        __syncthreads();
        #pragma unroll
        for (int k4 = 0; k4 < 32; k4 += 4) {
            float4 xv[8];
            #pragma unroll
            for (int i = 0; i < 8; ++i) xv[i] = *(const float4*)(&xs[r0 + i][k4]);
            float4 wv0 = *(const float4*)(&wsm[k4 + 0][c0]);
            float4 wv1 = *(const float4*)(&wsm[k4 + 1][c0]);
            float4 wv2 = *(const float4*)(&wsm[k4 + 2][c0]);
            float4 wv3 = *(const float4*)(&wsm[k4 + 3][c0]);
            #pragma unroll
            for (int i = 0; i < 8; ++i) {
                acc[i][0] += xv[i].x * wv0.x + xv[i].y * wv1.x + xv[i].z * wv2.x + xv[i].w * wv3.x;
                acc[i][1] += xv[i].x * wv0.y + xv[i].y * wv1.y + xv[i].z * wv2.y + xv[i].w * wv3.y;
                acc[i][2] += xv[i].x * wv0.z + xv[i].y * wv1.z + xv[i].z * wv2.z + xv[i].w * wv3.z;
                acc[i][3] += xv[i].x * wv0.w + xv[i].y * wv1.w + xv[i].z * wv2.w + xv[i].w * wv3.w;
            }
        }
        __syncthreads();
    }
    #pragma unroll
    for (int i = 0; i < 8; ++i) {
        int row = row0 + r0 + i;
        if (row < N) {
            float4 v = make_float4(acc[i][0], acc[i][1], acc[i][2], acc[i][3]);
            *(float4*)(y1 + (size_t)row * 128 + c0) = v;
        }
    }
}

// ---- Fused: h_i = relu(xl_i + mean(xr[nbr]) + b1);  y2_i = h_i @ [W2l|W2r] ----
// One wave per node. lane = feature (64). h_i lives in wave-private LDS row;
// GEMV: lane<40 owns output col pair (2*lane, 2*lane+1), W2 staged in LDS.

__global__ __launch_bounds__(256) void k_fused2(const float* __restrict__ y1,
                                                const int* __restrict__ csr,
                                                const int* __restrict__ off,
                                                const int* __restrict__ cnt,
                                                const float* __restrict__ b1,
                                                const float* __restrict__ W2l,
                                                const float* __restrict__ W2r,
                                                float* __restrict__ y2, int N) {
    __shared__ float wsm[64][80];    // [k][col], cols 0-39 = W2l, 40-79 = W2r
    __shared__ float hrow[4][64];    // per-wave h_i scratch
    int tid = threadIdx.x;
    // stage W2: 5120 floats = 1280 float4, 5 per thread
    #pragma unroll
    for (int it = 0; it < 5; ++it) {
        int idx = tid + it * 256;            // 0..1279
        int k = idx / 20;
        int cq = idx % 20;
        const float* s = (cq < 10) ? (W2l + (size_t)k * 40 + cq * 4)
                                   : (W2r + (size_t)k * 40 + (cq - 10) * 4);
        *(float4*)(&wsm[k][cq * 4]) = *(const float4*)s;
    }
    __syncthreads();

    int lane = tid & 63;
    int wv = tid >> 6;                       // wave in block, 0..3
    int wid = blockIdx.x * 4 + wv;
    int nw = gridDim.x * 4;
    float bl = b1[lane];
    int cl = (lane < 40) ? 2 * lane : 0;     // output col pair (guarded)

    for (int i = wid; i < N; i += nw) {
        int deg = cnt[i];
        int start = off[i];
        float a0 = 0.f, a1 = 0.f, a2 = 0.f, a3 = 0.f;
        for (int base = 0; base < deg; base += 64) {
            int m = min(64, deg - base);
            int s = (lane < m) ? csr[start + base + lane] : 0;
            int j = 0;
            for (; j + 4 <= m; j += 4) {
                int s0 = __shfl(s, j), s1 = __shfl(s, j + 1);
                int s2 = __shfl(s, j + 2), s3 = __shfl(s, j + 3);
                a0 += y1[(size_t)s0 * 128 + 64 + lane];
                a1 += y1[(size_t)s1 * 128 + 64 + lane];
                a2 += y1[(size_t)s2 * 128 + 64 + lane];
                a3 += y1[(size_t)s3 * 128 + 64 + lane];
            }
            for (; j < m; ++j) {
                int sj = __shfl(s, j);
                a0 += y1[(size_t)sj * 128 + 64 + lane];
            }
        }
        float mean = (a0 + a1 + a2 + a3) / (float)max(deg, 1);
        float hv = fmaxf(y1[(size_t)i * 128 + lane] + mean + bl, 0.f);

        // wave-private LDS: write h row, then GEMV (same-wave RAW, no barrier)
        hrow[wv][lane] = hv;
        float p0 = 0.f, p1 = 0.f;
        #pragma unroll
        for (int k4 = 0; k4 < 64; k4 += 4) {
            float4 hk = *(const float4*)(&hrow[wv][k4]);   // uniform addr -> broadcast
            float2 w0 = *(const float2*)(&wsm[k4 + 0][cl]);
            float2 w1 = *(const float2*)(&wsm[k4 + 1][cl]);
            float2 w2 = *(const float2*)(&wsm[k4 + 2][cl]);
            float2 w3 = *(const float2*)(&wsm[k4 + 3][cl]);
            p0 += hk.x * w0.x + hk.y * w1.x + hk.z * w2.x + hk.w * w3.x;
            p1 += hk.x * w0.y + hk.y * w1.y + hk.z * w2.y + hk.w * w3.y;
        }
        if (lane < 40)
            *(float2*)(y2 + (size_t)i * 80 + cl) = make_float2(p0, p1);
    }
}

// ---------------- Agg2 + bias + softmax -------------------------------------

__global__ void k_agg2(const float* __restrict__ y2, const int* __restrict__ csr,
                       const int* __restrict__ off, const int* __restrict__ cnt,
                       const float* __restrict__ b2, float* __restrict__ out, int N) {
    int lane = threadIdx.x & 63;
    int wid = (blockIdx.x * blockDim.x + threadIdx.x) >> 6;
    int nw = (gridDim.x * blockDim.x) >> 6;
    for (int i = wid; i < N; i += nw) {
        int deg = cnt[i];
        int start = off[i];
        float a0 = 0.f, a1 = 0.f, a2 = 0.f, a3 = 0.f;
        bool act = (lane < 40);
        for (int base = 0; base < deg; base += 64) {
            int m = min(64, deg - base);
            int s = (lane < m) ? csr[start + base + lane] : 0;
            int j = 0;
            for (; j + 4 <= m; j += 4) {
                int s0 = __shfl(s, j), s1 = __shfl(s, j + 1);
                int s2 = __shfl(s, j + 2), s3 = __shfl(s, j + 3);
                if (act) {
                    a0 += y2[(size_t)s0 * 80 + 40 + lane];
                    a1 += y2[(size_t)s1 * 80 + 40 + lane];
                    a2 += y2[(size_t)s2 * 80 + 40 + lane];
                    a3 += y2[(size_t)s3 * 80 + 40 + lane];
                }
            }
            for (; j < m; ++j) {
                int sj = __shfl(s, j);
                if (act) a0 += y2[(size_t)sj * 80 + 40 + lane];
            }
        }
        float logit = -INFINITY;
        if (act) {
            float mean = (a0 + a1 + a2 + a3) / (float)max(deg, 1);
            logit = y2[(size_t)i * 80 + lane] + mean + b2[lane];
        }
        float mx = logit;
        #pragma unroll
        for (int o = 32; o > 0; o >>= 1) mx = fmaxf(mx, __shfl_xor(mx, o));
        float e = act ? expf(logit - mx) : 0.f;
        float se = e;
        #pragma unroll
        for (int o = 32; o > 0; o >>= 1) se += __shfl_xor(se, o);
        if (act) out[(size_t)i * 40 + lane] = e / se;
    }
}

// ---------------- launch ----------------------------------------------------

extern "C" void kernel_launch(void* const* d_in, const int* in_sizes, int n_in,
                              void* d_out, int out_size, void* d_ws, size_t ws_size,
                              hipStream_t stream) {
    const float* x   = (const float*)d_in[0];
    const int*   ei  = (const int*)d_in[1];
    const float* W1l = (const float*)d_in[2];
    const float* W1r = (const float*)d_in[3];
    const float* b1  = (const float*)d_in[4];
    const float* W2l = (const float*)d_in[5];
    const float* W2r = (const float*)d_in[6];
    const float* b2  = (const float*)d_in[7];
    float* out = (float*)d_out;

    int N = in_sizes[0] / 256;
    int E = in_sizes[1] / 2;
    const int* srcp = ei;
    const int* dstp = ei + E;

    char* w = (char*)d_ws;
    auto alloc = [&](size_t bytes) {
        char* p = w;
        w += (bytes + 255) & ~(size_t)255;
        return p;
    };
    int nb = (N + 255) / 256;
    int*   cnt    = (int*)alloc((size_t)N * 4);
    int*   off    = (int*)alloc((size_t)N * 4);
    int*   cursor = (int*)alloc((size_t)N * 4);
    int*   bsum   = (int*)alloc((size_t)nb * 4);
    int*   csr    = (int*)alloc((size_t)E * 4);
    float* y1     = (float*)alloc((size_t)N * 128 * 4);
    float* y2     = (float*)alloc((size_t)N * 80 * 4);

    hipMemsetAsync(cnt, 0, (size_t)N * 4, stream);
    k_count<<<(E + 255) / 256, 256, 0, stream>>>(dstp, cnt, E);
    k_blocksum<<<nb, 256, 0, stream>>>(cnt, bsum, N);
    k_scanbsum<<<1, 512, 0, stream>>>(bsum, nb);
    k_scanfinal<<<nb, 256, 0, stream>>>(cnt, bsum, off, cursor, N);
    k_scatter<<<(E + 255) / 256, 256, 0, stream>>>(srcp, dstp, cursor, csr, E);

    k_gemm1<<<(N + 63) / 64, 256, 0, stream>>>(x, W1l, W1r, y1, N);
    k_fused2<<<1792, 256, 0, stream>>>(y1, csr, off, cnt, b1, W2l, W2r, y2, N);
    k_agg2<<<2048, 256, 0, stream>>>(y2, csr, off, cnt, b2, out, N);
}